// Round 4
// baseline (126.379 us; speedup 1.0000x reference)
//
#include <hip/hip_runtime.h>
#include <math.h>

#define N_QUBITS 4
#define N_LAYERS 6
#define NW (N_LAYERS * N_QUBITS)
#define M 4   // samples per thread in qeval

// ---------------------------------------------------------------------------
// Prep kernel (1 block): build W (16x16 complex) from the 24 RX gates + CNOT
// rings, form S_q = Re(W^dag Z_q W), contract to the 81-term multilinear table
//   out_q(x) = sum_{t in {I,Z,X}^4} C_q[t] * prod_p (1, cos x_p, sin x_p)[t_p]
// Layout: Ctab[t*4 + q]  (float4 per term t -> one load feeds all 4 outputs).
// ---------------------------------------------------------------------------
__global__ __launch_bounds__(256) void qprep_kernel(
    const float* __restrict__ weights, float* __restrict__ Ctab)
{
    __shared__ float Wr[16][16];
    __shared__ float Wi[16][16];
    __shared__ float S[4][16][16];
    __shared__ float wc[NW], ws[NW];
    const int tid = threadIdx.x;
    if (tid < NW) {
        float t = weights[tid] * 0.5f;
        wc[tid] = cosf(t);
        ws[tid] = sinf(t);
    }
    __syncthreads();

    // Phase 1: threads 0..15 build column `tid` of W (fully unrolled -> regs)
    if (tid < 16) {
        float re[16], im[16];
#pragma unroll
        for (int k = 0; k < 16; ++k) { re[k] = (k == tid) ? 1.f : 0.f; im[k] = 0.f; }
#pragma unroll
        for (int l = 0; l < N_LAYERS; ++l) {
#pragma unroll
            for (int q = 0; q < 4; ++q) {
                const float ct = wc[l * 4 + q], sn = ws[l * 4 + q];
                const int mask = 8 >> q;
#pragma unroll
                for (int idx = 0; idx < 16; ++idx) {
                    if (idx & mask) continue;
                    const int j = idx | mask;
                    float r0 = re[idx], u0 = im[idx], r1 = re[j], u1 = im[j];
                    re[idx] = ct * r0 + sn * u1; im[idx] = ct * u0 - sn * r1;
                    re[j]   = ct * r1 + sn * u0; im[j]   = ct * u1 - sn * r0;
                }
            }
#pragma unroll
            for (int q = 0; q < 4; ++q) {
                const int cm = 8 >> q, tm = 8 >> ((q + 1) & 3);
#pragma unroll
                for (int idx = 0; idx < 16; ++idx) {
                    if ((idx & cm) && !(idx & tm)) {
                        const int j = idx | tm;
                        float t0 = re[idx]; re[idx] = re[j]; re[j] = t0;
                        float t1 = im[idx]; im[idx] = im[j]; im[j] = t1;
                    }
                }
            }
        }
#pragma unroll
        for (int k = 0; k < 16; ++k) { Wr[k][tid] = re[k]; Wi[k][tid] = im[k]; }
    }
    __syncthreads();

    // Phase 2: thread (i,j): S_q[i][j] = sum_k z_q(k) Re(W[k,i] conj(W[k,j]))
    {
        const int i = tid >> 4, j = tid & 15;
        float acc0 = 0.f, acc1 = 0.f, acc2 = 0.f, acc3 = 0.f;
#pragma unroll
        for (int k = 0; k < 16; ++k) {
            const float prod = Wr[k][i] * Wr[k][j] + Wi[k][i] * Wi[k][j];
            acc0 += (k & 8) ? -prod : prod;
            acc1 += (k & 4) ? -prod : prod;
            acc2 += (k & 2) ? -prod : prod;
            acc3 += (k & 1) ? -prod : prod;
        }
        S[0][i][j] = acc0; S[1][i][j] = acc1; S[2][i][j] = acc2; S[3][i][j] = acc3;
    }
    __syncthreads();

    // Phase 3: C_q[t] = (1/16) sum_i (-1)^popc(i&zm) S_q[i][i^xm]
    if (tid < 81) {
        const int t1 = tid / 27, t2 = (tid / 9) % 3, t3 = (tid / 3) % 3, t4 = tid % 3;
        int zm = 0, xm = 0;
        if (t1 == 1) zm |= 8; else if (t1 == 2) xm |= 8;
        if (t2 == 1) zm |= 4; else if (t2 == 2) xm |= 4;
        if (t3 == 1) zm |= 2; else if (t3 == 2) xm |= 2;
        if (t4 == 1) zm |= 1; else if (t4 == 2) xm |= 1;
#pragma unroll
        for (int q = 0; q < 4; ++q) {
            float acc = 0.f;
#pragma unroll
            for (int i = 0; i < 16; ++i) {
                const float v = S[q][i][i ^ xm];
                acc += (__popc(i & zm) & 1) ? -v : v;
            }
            Ctab[tid * 4 + q] = acc * 0.0625f;   // float4-per-term layout
        }
    }
}

// ---------------------------------------------------------------------------
// Main kernel: vec4 Horner over the 81-term table. Coefficients staged in LDS
// (81 x float4 = 1.3 KB), read as same-address ds_read_b128 (broadcast, free
// of bank conflicts). M=4 samples/thread amortizes the 81 LDS reads.
// ---------------------------------------------------------------------------
__global__ __launch_bounds__(256) void qeval_kernel(
    const float* __restrict__ x, const float* __restrict__ Ctab,
    float* __restrict__ out, int B)
{
    __shared__ float4 Cs[81];
    const int tid = threadIdx.x;
    if (tid < 81) Cs[tid] = reinterpret_cast<const float4*>(Ctab)[tid];
    __syncthreads();

    const int base = blockIdx.x * (256 * M) + tid;

    float vc[M][4], vs[M][4];
#pragma unroll
    for (int m = 0; m < M; ++m) {
        const int b = base + m * 256;
        float4 xv = (b < B) ? reinterpret_cast<const float4*>(x)[b]
                            : make_float4(0.f, 0.f, 0.f, 0.f);
        vc[m][0] = __cosf(xv.x); vs[m][0] = __sinf(xv.x);
        vc[m][1] = __cosf(xv.y); vs[m][1] = __sinf(xv.y);
        vc[m][2] = __cosf(xv.z); vs[m][2] = __sinf(xv.z);
        vc[m][3] = __cosf(xv.w); vs[m][3] = __sinf(xv.w);
    }

    float4 s1[M];
#pragma unroll
    for (int m = 0; m < M; ++m) s1[m] = make_float4(0.f, 0.f, 0.f, 0.f);

#pragma unroll
    for (int t1 = 0; t1 < 3; ++t1) {
        float4 s2[M];
#pragma unroll
        for (int m = 0; m < M; ++m) s2[m] = make_float4(0.f, 0.f, 0.f, 0.f);
#pragma unroll
        for (int t2 = 0; t2 < 3; ++t2) {
            float4 s3[M];
#pragma unroll
            for (int m = 0; m < M; ++m) s3[m] = make_float4(0.f, 0.f, 0.f, 0.f);
#pragma unroll
            for (int t3 = 0; t3 < 3; ++t3) {
                const int b3 = ((t1 * 3 + t2) * 3 + t3) * 3;
                const float4 c0 = Cs[b3];
                const float4 c1 = Cs[b3 + 1];
                const float4 c2 = Cs[b3 + 2];
#pragma unroll
                for (int m = 0; m < M; ++m) {
                    const float a = vc[m][3], s = vs[m][3];
                    float4 e;
                    e.x = fmaf(c1.x, a, c0.x); e.y = fmaf(c1.y, a, c0.y);
                    e.z = fmaf(c1.z, a, c0.z); e.w = fmaf(c1.w, a, c0.w);
                    e.x = fmaf(c2.x, s, e.x);  e.y = fmaf(c2.y, s, e.y);
                    e.z = fmaf(c2.z, s, e.z);  e.w = fmaf(c2.w, s, e.w);
                    if (t3 == 0) {
                        s3[m].x += e.x; s3[m].y += e.y; s3[m].z += e.z; s3[m].w += e.w;
                    } else {
                        const float w = (t3 == 1) ? vc[m][2] : vs[m][2];
                        s3[m].x = fmaf(e.x, w, s3[m].x); s3[m].y = fmaf(e.y, w, s3[m].y);
                        s3[m].z = fmaf(e.z, w, s3[m].z); s3[m].w = fmaf(e.w, w, s3[m].w);
                    }
                }
            }
#pragma unroll
            for (int m = 0; m < M; ++m) {
                if (t2 == 0) {
                    s2[m].x += s3[m].x; s2[m].y += s3[m].y;
                    s2[m].z += s3[m].z; s2[m].w += s3[m].w;
                } else {
                    const float w = (t2 == 1) ? vc[m][1] : vs[m][1];
                    s2[m].x = fmaf(s3[m].x, w, s2[m].x); s2[m].y = fmaf(s3[m].y, w, s2[m].y);
                    s2[m].z = fmaf(s3[m].z, w, s2[m].z); s2[m].w = fmaf(s3[m].w, w, s2[m].w);
                }
            }
        }
#pragma unroll
        for (int m = 0; m < M; ++m) {
            if (t1 == 0) {
                s1[m].x += s2[m].x; s1[m].y += s2[m].y;
                s1[m].z += s2[m].z; s1[m].w += s2[m].w;
            } else {
                const float w = (t1 == 1) ? vc[m][0] : vs[m][0];
                s1[m].x = fmaf(s2[m].x, w, s1[m].x); s1[m].y = fmaf(s2[m].y, w, s1[m].y);
                s1[m].z = fmaf(s2[m].z, w, s1[m].z); s1[m].w = fmaf(s2[m].w, w, s1[m].w);
            }
        }
    }

#pragma unroll
    for (int m = 0; m < M; ++m) {
        const int b = base + m * 256;
        if (b < B) reinterpret_cast<float4*>(out)[b] = s1[m];
    }
}

extern "C" void kernel_launch(void* const* d_in, const int* in_sizes, int n_in,
                              void* d_out, int out_size, void* d_ws, size_t ws_size,
                              hipStream_t stream) {
    const float* x = (const float*)d_in[0];
    const float* weights = (const float*)d_in[1];
    float* out = (float*)d_out;
    float* Ctab = (float*)d_ws;   // 324 floats, float4-per-term
    const int B = in_sizes[0] / 4;

    qprep_kernel<<<1, 256, 0, stream>>>(weights, Ctab);

    const int spb = 256 * M;
    const int grid = (B + spb - 1) / spb;
    qeval_kernel<<<grid, 256, 0, stream>>>(x, Ctab, out, B);
}

// Round 5
// 81.694 us; speedup vs baseline: 1.5470x; 1.5470x over previous
//
#include <hip/hip_runtime.h>
#include <math.h>

#define N_QUBITS 4
#define N_LAYERS 6
#define NW (N_LAYERS * N_QUBITS)

// ---------------------------------------------------------------------------
// Prep kernel (1 block): build W (16x16 complex) from the 24 RX gates + CNOT
// rings, form S_q = Re(W^dag Z_q W), contract to the 81-term multilinear table
//   out_q(x) = sum_{t in {I,Z,X}^4} C_q[t] * prod_p (1, cos x_p, sin x_p)[t_p]
// Layout: Ctab[t*4 + q]  (float4 per term t -> one load feeds all 4 outputs).
// ---------------------------------------------------------------------------
__global__ __launch_bounds__(256) void qprep_kernel(
    const float* __restrict__ weights, float* __restrict__ Ctab)
{
    __shared__ float Wr[16][16];
    __shared__ float Wi[16][16];
    __shared__ float S[4][16][16];
    __shared__ float wc[NW], ws[NW];
    const int tid = threadIdx.x;
    if (tid < NW) {
        float t = weights[tid] * 0.5f;
        wc[tid] = cosf(t);
        ws[tid] = sinf(t);
    }
    __syncthreads();

    // Phase 1: threads 0..15 build column `tid` of W (fully unrolled -> regs)
    if (tid < 16) {
        float re[16], im[16];
#pragma unroll
        for (int k = 0; k < 16; ++k) { re[k] = (k == tid) ? 1.f : 0.f; im[k] = 0.f; }
#pragma unroll
        for (int l = 0; l < N_LAYERS; ++l) {
#pragma unroll
            for (int q = 0; q < 4; ++q) {
                const float ct = wc[l * 4 + q], sn = ws[l * 4 + q];
                const int mask = 8 >> q;
#pragma unroll
                for (int idx = 0; idx < 16; ++idx) {
                    if (idx & mask) continue;
                    const int j = idx | mask;
                    float r0 = re[idx], u0 = im[idx], r1 = re[j], u1 = im[j];
                    re[idx] = ct * r0 + sn * u1; im[idx] = ct * u0 - sn * r1;
                    re[j]   = ct * r1 + sn * u0; im[j]   = ct * u1 - sn * r0;
                }
            }
#pragma unroll
            for (int q = 0; q < 4; ++q) {
                const int cm = 8 >> q, tm = 8 >> ((q + 1) & 3);
#pragma unroll
                for (int idx = 0; idx < 16; ++idx) {
                    if ((idx & cm) && !(idx & tm)) {
                        const int j = idx | tm;
                        float t0 = re[idx]; re[idx] = re[j]; re[j] = t0;
                        float t1 = im[idx]; im[idx] = im[j]; im[j] = t1;
                    }
                }
            }
        }
#pragma unroll
        for (int k = 0; k < 16; ++k) { Wr[k][tid] = re[k]; Wi[k][tid] = im[k]; }
    }
    __syncthreads();

    // Phase 2: thread (i,j): S_q[i][j] = sum_k z_q(k) Re(W[k,i] conj(W[k,j]))
    {
        const int i = tid >> 4, j = tid & 15;
        float acc0 = 0.f, acc1 = 0.f, acc2 = 0.f, acc3 = 0.f;
#pragma unroll
        for (int k = 0; k < 16; ++k) {
            const float prod = Wr[k][i] * Wr[k][j] + Wi[k][i] * Wi[k][j];
            acc0 += (k & 8) ? -prod : prod;
            acc1 += (k & 4) ? -prod : prod;
            acc2 += (k & 2) ? -prod : prod;
            acc3 += (k & 1) ? -prod : prod;
        }
        S[0][i][j] = acc0; S[1][i][j] = acc1; S[2][i][j] = acc2; S[3][i][j] = acc3;
    }
    __syncthreads();

    // Phase 3: C_q[t] = (1/16) sum_i (-1)^popc(i&zm) S_q[i][i^xm]
    if (tid < 81) {
        const int t1 = tid / 27, t2 = (tid / 9) % 3, t3 = (tid / 3) % 3, t4 = tid % 3;
        int zm = 0, xm = 0;
        if (t1 == 1) zm |= 8; else if (t1 == 2) xm |= 8;
        if (t2 == 1) zm |= 4; else if (t2 == 2) xm |= 4;
        if (t3 == 1) zm |= 2; else if (t3 == 2) xm |= 2;
        if (t4 == 1) zm |= 1; else if (t4 == 2) xm |= 1;
#pragma unroll
        for (int q = 0; q < 4; ++q) {
            float acc = 0.f;
#pragma unroll
            for (int i = 0; i < 16; ++i) {
                const float v = S[q][i][i ^ xm];
                acc += (__popc(i & zm) & 1) ? -v : v;
            }
            Ctab[tid * 4 + q] = acc * 0.0625f;   // float4-per-term layout
        }
    }
}

// ---------------------------------------------------------------------------
// Main kernel: M=1 sample/thread (small live set, no spill — R4's M=4 spilled
// 65 MB of scratch at 256 VGPR). vec4 Horner over the 81-term table; each
// float4 coefficient load feeds all 4 outputs. Coefficient addresses are
// thread-invariant -> uniform/scalar load path + L1 hits.
// __launch_bounds__(256,4): cap at <=128 VGPR so hoisting can't spill.
// ---------------------------------------------------------------------------
__global__ __launch_bounds__(256, 4) void qeval_kernel(
    const float* __restrict__ x, const float* __restrict__ Ctab,
    float* __restrict__ out, int B)
{
    const int b = blockIdx.x * 256 + threadIdx.x;
    if (b >= B) return;

    const float4 xv = reinterpret_cast<const float4*>(x)[b];
    const float c0q = __cosf(xv.x), s0q = __sinf(xv.x);
    const float c1q = __cosf(xv.y), s1q = __sinf(xv.y);
    const float c2q = __cosf(xv.z), s2q = __sinf(xv.z);
    const float c3q = __cosf(xv.w), s3q = __sinf(xv.w);

    const float4* __restrict__ C4 = reinterpret_cast<const float4*>(Ctab);

    float4 a1 = make_float4(0.f, 0.f, 0.f, 0.f);
#pragma unroll
    for (int t1 = 0; t1 < 3; ++t1) {
        float4 a2 = make_float4(0.f, 0.f, 0.f, 0.f);
#pragma unroll
        for (int t2 = 0; t2 < 3; ++t2) {
            float4 a3 = make_float4(0.f, 0.f, 0.f, 0.f);
#pragma unroll
            for (int t3 = 0; t3 < 3; ++t3) {
                const int base = ((t1 * 3 + t2) * 3 + t3) * 3;
                const float4 k0 = C4[base];
                const float4 k1 = C4[base + 1];
                const float4 k2 = C4[base + 2];
                float4 e;
                e.x = fmaf(k1.x, c3q, k0.x); e.y = fmaf(k1.y, c3q, k0.y);
                e.z = fmaf(k1.z, c3q, k0.z); e.w = fmaf(k1.w, c3q, k0.w);
                e.x = fmaf(k2.x, s3q, e.x);  e.y = fmaf(k2.y, s3q, e.y);
                e.z = fmaf(k2.z, s3q, e.z);  e.w = fmaf(k2.w, s3q, e.w);
                if (t3 == 0) {
                    a3.x += e.x; a3.y += e.y; a3.z += e.z; a3.w += e.w;
                } else {
                    const float w = (t3 == 1) ? c2q : s2q;
                    a3.x = fmaf(e.x, w, a3.x); a3.y = fmaf(e.y, w, a3.y);
                    a3.z = fmaf(e.z, w, a3.z); a3.w = fmaf(e.w, w, a3.w);
                }
            }
            if (t2 == 0) {
                a2.x += a3.x; a2.y += a3.y; a2.z += a3.z; a2.w += a3.w;
            } else {
                const float w = (t2 == 1) ? c1q : s1q;
                a2.x = fmaf(a3.x, w, a2.x); a2.y = fmaf(a3.y, w, a2.y);
                a2.z = fmaf(a3.z, w, a2.z); a2.w = fmaf(a3.w, w, a2.w);
            }
        }
        if (t1 == 0) {
            a1.x += a2.x; a1.y += a2.y; a1.z += a2.z; a1.w += a2.w;
        } else {
            const float w = (t1 == 1) ? c0q : s0q;
            a1.x = fmaf(a2.x, w, a1.x); a1.y = fmaf(a2.y, w, a1.y);
            a1.z = fmaf(a2.z, w, a1.z); a1.w = fmaf(a2.w, w, a1.w);
        }
    }

    reinterpret_cast<float4*>(out)[b] = a1;
}

extern "C" void kernel_launch(void* const* d_in, const int* in_sizes, int n_in,
                              void* d_out, int out_size, void* d_ws, size_t ws_size,
                              hipStream_t stream) {
    const float* x = (const float*)d_in[0];
    const float* weights = (const float*)d_in[1];
    float* out = (float*)d_out;
    float* Ctab = (float*)d_ws;   // 324 floats, float4-per-term
    const int B = in_sizes[0] / 4;

    qprep_kernel<<<1, 256, 0, stream>>>(weights, Ctab);

    const int grid = (B + 255) / 256;
    qeval_kernel<<<grid, 256, 0, stream>>>(x, Ctab, out, B);
}

// Round 6
// 80.722 us; speedup vs baseline: 1.5656x; 1.0120x over previous
//
#include <hip/hip_runtime.h>
#include <math.h>

#define N_QUBITS 4
#define N_LAYERS 6
#define NW (N_LAYERS * N_QUBITS)

// ---------------------------------------------------------------------------
// Prep kernel (1 block): build W (16x16 complex) from the 24 RX gates + CNOT
// rings, form S_q = Re(W^dag Z_q W), contract to the 81-term multilinear table
//   out_q(x) = sum_{t in {I,Z,X}^4} C_q[t] * prod_p (1, cos x_p, sin x_p)[t_p]
// Layout: Ctab[t*4 + q]  (float4 per term t -> one load feeds all 4 outputs).
// Layer loop kept rolled (unroll 1) to keep the code ~2 KB (icache-friendly);
// all state indices inside the body are still compile-time constants.
// ---------------------------------------------------------------------------
__global__ __launch_bounds__(256) void qprep_kernel(
    const float* __restrict__ weights, float* __restrict__ Ctab)
{
    __shared__ float Wr[16][16];
    __shared__ float Wi[16][16];
    __shared__ float S[4][16][16];
    __shared__ float wc[NW], ws[NW];
    const int tid = threadIdx.x;
    if (tid < NW) {
        float t = weights[tid] * 0.5f;
        wc[tid] = cosf(t);
        ws[tid] = sinf(t);
    }
    __syncthreads();

    // Phase 1: threads 0..15 build column `tid` of W
    if (tid < 16) {
        float re[16], im[16];
#pragma unroll
        for (int k = 0; k < 16; ++k) { re[k] = (k == tid) ? 1.f : 0.f; im[k] = 0.f; }
#pragma unroll 1
        for (int l = 0; l < N_LAYERS; ++l) {
#pragma unroll
            for (int q = 0; q < 4; ++q) {
                const float ct = wc[l * 4 + q], sn = ws[l * 4 + q];
                const int mask = 8 >> q;
#pragma unroll
                for (int idx = 0; idx < 16; ++idx) {
                    if (idx & mask) continue;
                    const int j = idx | mask;
                    float r0 = re[idx], u0 = im[idx], r1 = re[j], u1 = im[j];
                    re[idx] = ct * r0 + sn * u1; im[idx] = ct * u0 - sn * r1;
                    re[j]   = ct * r1 + sn * u0; im[j]   = ct * u1 - sn * r0;
                }
            }
#pragma unroll
            for (int q = 0; q < 4; ++q) {
                const int cm = 8 >> q, tm = 8 >> ((q + 1) & 3);
#pragma unroll
                for (int idx = 0; idx < 16; ++idx) {
                    if ((idx & cm) && !(idx & tm)) {
                        const int j = idx | tm;
                        float t0 = re[idx]; re[idx] = re[j]; re[j] = t0;
                        float t1 = im[idx]; im[idx] = im[j]; im[j] = t1;
                    }
                }
            }
        }
#pragma unroll
        for (int k = 0; k < 16; ++k) { Wr[k][tid] = re[k]; Wi[k][tid] = im[k]; }
    }
    __syncthreads();

    // Phase 2: thread (i,j): S_q[i][j] = sum_k z_q(k) Re(W[k,i] conj(W[k,j]))
    {
        const int i = tid >> 4, j = tid & 15;
        float acc0 = 0.f, acc1 = 0.f, acc2 = 0.f, acc3 = 0.f;
#pragma unroll
        for (int k = 0; k < 16; ++k) {
            const float prod = Wr[k][i] * Wr[k][j] + Wi[k][i] * Wi[k][j];
            acc0 += (k & 8) ? -prod : prod;
            acc1 += (k & 4) ? -prod : prod;
            acc2 += (k & 2) ? -prod : prod;
            acc3 += (k & 1) ? -prod : prod;
        }
        S[0][i][j] = acc0; S[1][i][j] = acc1; S[2][i][j] = acc2; S[3][i][j] = acc3;
    }
    __syncthreads();

    // Phase 3: C_q[t] = (1/16) sum_i (-1)^popc(i&zm) S_q[i][i^xm]
    if (tid < 81) {
        const int t1 = tid / 27, t2 = (tid / 9) % 3, t3 = (tid / 3) % 3, t4 = tid % 3;
        int zm = 0, xm = 0;
        if (t1 == 1) zm |= 8; else if (t1 == 2) xm |= 8;
        if (t2 == 1) zm |= 4; else if (t2 == 2) xm |= 4;
        if (t3 == 1) zm |= 2; else if (t3 == 2) xm |= 2;
        if (t4 == 1) zm |= 1; else if (t4 == 2) xm |= 1;
#pragma unroll
        for (int q = 0; q < 4; ++q) {
            float acc = 0.f;
#pragma unroll
            for (int i = 0; i < 16; ++i) {
                const float v = S[q][i][i ^ xm];
                acc += (__popc(i & zm) & 1) ? -v : v;
            }
            Ctab[tid * 4 + q] = acc * 0.0625f;   // float4-per-term layout
        }
    }
}

// ---------------------------------------------------------------------------
// Main kernel: out4 = sum_i u9[i] * ( sum_j C4[i*9+j] * w9[j] )
//   u9 = (1,c1,s1) x (1,c0... ) -- precisely u9[t1*3+t2] = v0[t1]*v1[t2],
//   w9[t3*3+t4] = v2[t3]*v3[t4], with vp = {1, cos x_p, sin x_p}.
// Features u9/w9 live in VGPRs; coefficients are wave-uniform (scalar) so
// every FMA is v_fma(sgpr, vgpr, vgpr) -- exactly 1 SGPR operand, no movs
// (R5's Horner form needed 2 SGPR operands per FMA -> v_mov storm).
// ~380 VALU ops/thread; live set ~45 VGPR.
// ---------------------------------------------------------------------------
__global__ __launch_bounds__(256, 6) void qeval_kernel(
    const float* __restrict__ x, const float* __restrict__ Ctab,
    float* __restrict__ out, int B)
{
    const int b = blockIdx.x * 256 + threadIdx.x;
    if (b >= B) return;

    const float4 xv = reinterpret_cast<const float4*>(x)[b];
    const float c0 = __cosf(xv.x), s0 = __sinf(xv.x);
    const float c1 = __cosf(xv.y), s1 = __sinf(xv.y);
    const float c2 = __cosf(xv.z), s2 = __sinf(xv.z);
    const float c3 = __cosf(xv.w), s3 = __sinf(xv.w);

    // u9[t1*3+t2] = v0[t1]*v1[t2];  w9[t3*3+t4] = v2[t3]*v3[t4]
    float u9[9], w9[9];
    u9[0] = 1.f;  u9[1] = c1;      u9[2] = s1;
    u9[3] = c0;   u9[4] = c0 * c1; u9[5] = c0 * s1;
    u9[6] = s0;   u9[7] = s0 * c1; u9[8] = s0 * s1;
    w9[0] = 1.f;  w9[1] = c3;      w9[2] = s3;
    w9[3] = c2;   w9[4] = c2 * c3; w9[5] = c2 * s3;
    w9[6] = s2;   w9[7] = s2 * c3; w9[8] = s2 * s3;

    const float4* __restrict__ C4 = reinterpret_cast<const float4*>(Ctab);

    float4 o = make_float4(0.f, 0.f, 0.f, 0.f);
#pragma unroll
    for (int i = 0; i < 9; ++i) {
        float4 t = make_float4(0.f, 0.f, 0.f, 0.f);
#pragma unroll
        for (int j = 0; j < 9; ++j) {
            const float4 c = C4[i * 9 + j];   // wave-uniform -> scalar load
            const float w = w9[j];
            t.x = fmaf(c.x, w, t.x);
            t.y = fmaf(c.y, w, t.y);
            t.z = fmaf(c.z, w, t.z);
            t.w = fmaf(c.w, w, t.w);
        }
        const float u = u9[i];
        o.x = fmaf(t.x, u, o.x);
        o.y = fmaf(t.y, u, o.y);
        o.z = fmaf(t.z, u, o.z);
        o.w = fmaf(t.w, u, o.w);
    }

    reinterpret_cast<float4*>(out)[b] = o;
}

extern "C" void kernel_launch(void* const* d_in, const int* in_sizes, int n_in,
                              void* d_out, int out_size, void* d_ws, size_t ws_size,
                              hipStream_t stream) {
    const float* x = (const float*)d_in[0];
    const float* weights = (const float*)d_in[1];
    float* out = (float*)d_out;
    float* Ctab = (float*)d_ws;   // 324 floats, float4-per-term
    const int B = in_sizes[0] / 4;

    qprep_kernel<<<1, 256, 0, stream>>>(weights, Ctab);

    const int grid = (B + 255) / 256;
    qeval_kernel<<<grid, 256, 0, stream>>>(x, Ctab, out, B);
}